// Round 1
// baseline (1298.933 us; speedup 1.0000x reference)
//
#include <hip/hip_runtime.h>
#include <math.h>

// Problem constants (fixed by setup_inputs)
#define B_SZ 8
#define IMG_H 64
#define IMG_W 64
#define N_TOK 4096          // 64*64
#define C_DIM 512
#define HEADS 16
#define HDIM 32
#define M_ROWS (B_SZ * N_TOK)   // 32768
#define QK_COLS (2 * C_DIM)     // 1024

// theta coefficient: -ln(10000)/128
#define THETA_COEF (-0.07195578415606394f)

// ---------------------------------------------------------------------------
// Pass 1: qk = x @ W^T + b, fused RoPE + (elu+1) + /softplus(scale)
// writes qW (ws) and kW (d_out used as scratch)
// Tiled fp32 GEMM: BM=64, BN=64, BK=16, 256 threads, 4x4 per thread
// ---------------------------------------------------------------------------
#define BM 64
#define BN 64
#define BK 16
#define LDP 68   // padded LDS stride (16B aligned)

__global__ __launch_bounds__(256) void gemm_rope_kernel(
    const float* __restrict__ x,       // (32768, 512)
    const float* __restrict__ Wqk,     // (1024, 512)
    const float* __restrict__ bqk,     // (1024)
    const float* __restrict__ scale_p, // (512)
    float* __restrict__ qW,            // (32768, 512)
    float* __restrict__ kW)            // (32768, 512)
{
    __shared__ float As[BK][LDP];
    __shared__ float Bs[BK][LDP];
    const int tid = threadIdx.x;
    const int tx = tid & 15;
    const int ty = tid >> 4;
    const int m0 = blockIdx.x * BM;
    const int c0blk = blockIdx.y * BN;

    const int lr = tid >> 2;      // 0..63 tile row
    const int lc4 = tid & 3;      // float4 index in K-chunk

    float acc[4][4] = {};

    for (int k0 = 0; k0 < C_DIM; k0 += BK) {
        float4 av = *(const float4*)(x + (size_t)(m0 + lr) * C_DIM + k0 + lc4 * 4);
        float4 bv = *(const float4*)(Wqk + (size_t)(c0blk + lr) * C_DIM + k0 + lc4 * 4);
        __syncthreads();
        As[lc4 * 4 + 0][lr] = av.x;
        As[lc4 * 4 + 1][lr] = av.y;
        As[lc4 * 4 + 2][lr] = av.z;
        As[lc4 * 4 + 3][lr] = av.w;
        Bs[lc4 * 4 + 0][lr] = bv.x;
        Bs[lc4 * 4 + 1][lr] = bv.y;
        Bs[lc4 * 4 + 2][lr] = bv.z;
        Bs[lc4 * 4 + 3][lr] = bv.w;
        __syncthreads();
#pragma unroll
        for (int kk = 0; kk < BK; ++kk) {
            float4 a4 = *(const float4*)&As[kk][ty * 4];
            float4 b4 = *(const float4*)&Bs[kk][tx * 4];
            float a[4] = {a4.x, a4.y, a4.z, a4.w};
            float b[4] = {b4.x, b4.y, b4.z, b4.w};
#pragma unroll
            for (int i = 0; i < 4; ++i)
#pragma unroll
                for (int j = 0; j < 4; ++j)
                    acc[i][j] += a[i] * b[j];
        }
    }

    // Epilogue: bias + RoPE + elu+1 + /softplus(scale)
    const int c0 = c0blk + tx * 4;
    float bias4[4], spv4[4], theta4[4];
    int useI4[4];
#pragma unroll
    for (int jj = 0; jj < 4; ++jj) {
        int c = c0 + jj;
        int ch = c & 511;
        bias4[jj] = bqk[c];
        spv4[jj] = log1pf(expf(scale_p[ch]));
        int tt = ch >> 1;
        useI4[jj] = (tt < 128) ? 1 : 0;
        theta4[jj] = expf((float)(tt & 127) * THETA_COEF);
    }
    float* dst = (c0 < C_DIM) ? qW : kW;
    const int ch0 = c0 & 511;

#pragma unroll
    for (int ii = 0; ii < 4; ++ii) {
        int m = m0 + ty * 4 + ii;
        int n = m & (N_TOK - 1);
        float pi = (float)(n >> 6);
        float pj = (float)(n & 63);
        float vals[4];
#pragma unroll
        for (int jp = 0; jp < 2; ++jp) {
            int j0 = jp * 2;
            float re = acc[ii][j0] + bias4[j0];
            float im = acc[ii][j0 + 1] + bias4[j0 + 1];
            float pos = useI4[j0] ? pi : pj;
            float ang = pos * theta4[j0];
            float sv, cv;
            sincosf(ang, &sv, &cv);
            float r2 = re * cv - im * sv;
            float i2 = im * cv + re * sv;
            r2 = (r2 > 0.f) ? (r2 + 1.f) : expf(r2);   // elu + 1
            i2 = (i2 > 0.f) ? (i2 + 1.f) : expf(i2);
            vals[j0] = r2 / spv4[j0];
            vals[j0 + 1] = i2 / spv4[j0 + 1];
        }
        *(float4*)(dst + (size_t)m * C_DIM + ch0) =
            make_float4(vals[0], vals[1], vals[2], vals[3]);
    }
}

// ---------------------------------------------------------------------------
// Pass 2: per-row norms -> s = ||v|| / ||v^3||  (for q and k)
// 4 rows per 256-thread block, one wave per row
// ---------------------------------------------------------------------------
__global__ __launch_bounds__(256) void norm_kernel(
    const float* __restrict__ qW, const float* __restrict__ kW,
    float* __restrict__ sq, float* __restrict__ sk)
{
    int wave = threadIdx.x >> 6;
    int lane = threadIdx.x & 63;
    int m = blockIdx.x * 4 + wave;
    const float* qr = qW + (size_t)m * C_DIM;
    const float* kr = kW + (size_t)m * C_DIM;
    float q2 = 0.f, q6 = 0.f, k2 = 0.f, k6 = 0.f;
#pragma unroll
    for (int l = 0; l < 8; ++l) {
        float q = qr[lane + l * 64];
        float k = kr[lane + l * 64];
        float qq = q * q, kk = k * k;
        q2 += qq;
        k2 += kk;
        q6 += qq * qq * qq;
        k6 += kk * kk * kk;
    }
#pragma unroll
    for (int off = 32; off > 0; off >>= 1) {
        q2 += __shfl_down(q2, off);
        q6 += __shfl_down(q6, off);
        k2 += __shfl_down(k2, off);
        k6 += __shfl_down(k6, off);
    }
    if (lane == 0) {
        sq[m] = sqrtf(q2) / sqrtf(q6);
        sk[m] = sqrtf(k2) / sqrtf(k6);
    }
}

// ---------------------------------------------------------------------------
// Pass 3a: partial kv[d][e] = sum_n k_f[n,d]*v[n,e] and km[d] = sum_n k_f[n,d]
// grid: 512 blocks = (b*16+h)*4 + split, each handles 1024 tokens
// ---------------------------------------------------------------------------
__global__ __launch_bounds__(256) void kv_partial_kernel(
    const float* __restrict__ x, const float* __restrict__ kW,
    const float* __restrict__ sk,
    float* __restrict__ kvp, float* __restrict__ kmp)
{
    int g = blockIdx.x >> 2;       // (b*16+h)
    int split = blockIdx.x & 3;
    int b = g >> 4, h = g & 15;
    int n_start = split * 1024;

    __shared__ float kf[64][36];
    __shared__ float vv[64][36];

    int t = threadIdx.x;
    int col = t & 31, rowb = t >> 5;
    int e = t & 31, d0 = (t >> 5) * 4;
    float acc[4] = {0.f, 0.f, 0.f, 0.f};
    float kmacc = 0.f;

    for (int n0 = n_start; n0 < n_start + 1024; n0 += 64) {
        __syncthreads();
#pragma unroll
        for (int r = 0; r < 8; ++r) {
            int row = r * 8 + rowb;
            int n = n0 + row;
            size_t base = ((size_t)(b * N_TOK + n)) * C_DIM + h * HDIM + col;
            float kvl = kW[base];
            float skv = sk[b * N_TOK + n];
            kf[row][col] = kvl * kvl * kvl * skv;
            vv[row][col] = x[base];
        }
        __syncthreads();
        for (int nn = 0; nn < 64; ++nn) {
            float vval = vv[nn][e];
            float4 k4 = *(const float4*)&kf[nn][d0];
            acc[0] += k4.x * vval;
            acc[1] += k4.y * vval;
            acc[2] += k4.z * vval;
            acc[3] += k4.w * vval;
        }
        if (t < 32) {
            for (int nn = 0; nn < 64; ++nn) kmacc += kf[nn][t];
        }
    }
    size_t pbase = (size_t)blockIdx.x * 1024;
#pragma unroll
    for (int di = 0; di < 4; ++di)
        kvp[pbase + (size_t)(d0 + di) * 32 + e] = acc[di];
    if (t < 32) kmp[blockIdx.x * 32 + t] = kmacc;
}

// Pass 3b: reduce the 4 splits; scale by 1/N
__global__ __launch_bounds__(256) void kv_reduce_kernel(
    const float* __restrict__ kvp, const float* __restrict__ kmp,
    float* __restrict__ kv, float* __restrict__ km)
{
    int g = blockIdx.x;   // 128
    int t = threadIdx.x;
    for (int idx = t; idx < 1024; idx += 256) {
        float s = 0.f;
#pragma unroll
        for (int sp = 0; sp < 4; ++sp)
            s += kvp[((size_t)(g * 4 + sp)) * 1024 + idx];
        kv[(size_t)g * 1024 + idx] = s * (1.0f / 4096.0f);
    }
    if (t < 32) {
        float s = 0.f;
#pragma unroll
        for (int sp = 0; sp < 4; ++sp) s += kmp[(g * 4 + sp) * 32 + t];
        km[g * 32 + t] = s * (1.0f / 4096.0f);
    }
}

// ---------------------------------------------------------------------------
// Pass 4: out[b,n,h*32+e] = z * sum_d q_f[n,d] kv[d,e],  z = 1/(q_f . km + 1e-6)
// grid (128, 32): (b*16+h, n-tile of 128)
// ---------------------------------------------------------------------------
__global__ __launch_bounds__(256) void attn_out_kernel(
    const float* __restrict__ qW, const float* __restrict__ sq,
    const float* __restrict__ kv, const float* __restrict__ km,
    float* __restrict__ out)
{
    int g = blockIdx.x;
    int b = g >> 4, h = g & 15;
    int n0 = blockIdx.y * 128;

    __shared__ float kvs[32][33];
    __shared__ float kms[32];
    __shared__ float qf[8][33];

    int t = threadIdx.x;
    for (int idx = t; idx < 1024; idx += 256)
        kvs[idx >> 5][idx & 31] = kv[(size_t)g * 1024 + idx];
    if (t < 32) kms[t] = km[g * 32 + t];
    __syncthreads();

    int e = t & 31, nl = t >> 5;
    for (int chunk = 0; chunk < 128; chunk += 8) {
        int n = n0 + chunk + nl;
        size_t base = ((size_t)(b * N_TOK + n)) * C_DIM + h * HDIM;
        float q = qW[base + e];
        qf[nl][e] = q * q * q * sq[b * N_TOK + n];
        __syncthreads();
        float s1 = 0.f, s2 = 0.f;
#pragma unroll
        for (int d = 0; d < 32; ++d) {
            float qd = qf[nl][d];
            s1 += qd * kvs[d][e];
            s2 += qd * kms[d];
        }
        float z = 1.0f / (s2 + 1e-6f);
        out[base + e] = s1 * z;
        __syncthreads();
    }
}

// ---------------------------------------------------------------------------
// Pass 5: out += depthwise conv5x5(x) + bias   (channel kernel = dwc_w[c%32])
// ---------------------------------------------------------------------------
__global__ __launch_bounds__(256) void conv_kernel(
    const float* __restrict__ x, const float* __restrict__ w,
    const float* __restrict__ bias, float* __restrict__ out)
{
    size_t idx = (size_t)blockIdx.x * 256 + threadIdx.x;
    int c = (int)(idx & 511);
    size_t bn = idx >> 9;
    int n = (int)(bn & (N_TOK - 1));
    int b = (int)(bn >> 12);
    int i = n >> 6, j = n & 63;
    int o = c & 31;
    float accv = bias[o];
#pragma unroll
    for (int ki = 0; ki < 5; ++ki) {
        int ii = i + ki - 2;
        if (ii < 0 || ii >= IMG_H) continue;
#pragma unroll
        for (int kj = 0; kj < 5; ++kj) {
            int jj = j + kj - 2;
            if (jj < 0 || jj >= IMG_W) continue;
            accv += w[o * 25 + ki * 5 + kj] *
                    x[((size_t)(b * N_TOK) + ii * 64 + jj) * C_DIM + c];
        }
    }
    out[idx] += accv;
}

// ---------------------------------------------------------------------------
extern "C" void kernel_launch(void* const* d_in, const int* in_sizes, int n_in,
                              void* d_out, int out_size, void* d_ws, size_t ws_size,
                              hipStream_t stream) {
    const float* x       = (const float*)d_in[0];
    const float* Wqk     = (const float*)d_in[1];
    const float* bqk     = (const float*)d_in[2];
    const float* scale_p = (const float*)d_in[3];
    const float* dwc_w   = (const float*)d_in[4];
    const float* dwc_b   = (const float*)d_in[5];
    float* out = (float*)d_out;
    float* ws = (float*)d_ws;

    // workspace layout (floats): qW | sq | sk | kvp | kmp | kv | km  (~70 MB)
    float* qW  = ws;
    float* sq  = qW + (size_t)M_ROWS * C_DIM;       // +16,777,216
    float* sk  = sq + M_ROWS;                        // +32768
    float* kvp = sk + M_ROWS;                        // +32768
    float* kmp = kvp + 512 * 1024;                   // +524288
    float* kv  = kmp + 512 * 32;                     // +16384
    float* km  = kv + 128 * 1024;                    // +131072
    float* kW  = out;   // k staged in d_out; fully consumed before pass 4 overwrites

    dim3 g1(M_ROWS / BM, QK_COLS / BN);
    gemm_rope_kernel<<<g1, 256, 0, stream>>>(x, Wqk, bqk, scale_p, qW, kW);

    norm_kernel<<<M_ROWS / 4, 256, 0, stream>>>(qW, kW, sq, sk);

    kv_partial_kernel<<<512, 256, 0, stream>>>(x, kW, sk, kvp, kmp);
    kv_reduce_kernel<<<128, 256, 0, stream>>>(kvp, kmp, kv, km);

    dim3 g4(128, 32);
    attn_out_kernel<<<g4, 256, 0, stream>>>(qW, sq, kv, km, out);

    conv_kernel<<<(M_ROWS * C_DIM) / 256, 256, 0, stream>>>(x, dwc_w, dwc_b, out);
}

// Round 2
// 1217.459 us; speedup vs baseline: 1.0669x; 1.0669x over previous
//
#include <hip/hip_runtime.h>
#include <math.h>

// Problem constants (fixed by setup_inputs)
#define B_SZ 8
#define IMG_H 64
#define IMG_W 64
#define N_TOK 4096          // 64*64
#define C_DIM 512
#define HEADS 16
#define HDIM 32
#define M_ROWS (B_SZ * N_TOK)   // 32768
#define QK_COLS (2 * C_DIM)     // 1024

// theta coefficient: -ln(10000)/128
#define THETA_COEF (-0.07195578415606394f)

typedef __attribute__((ext_vector_type(8))) __bf16 bf16x8;
typedef __attribute__((ext_vector_type(4))) float f32x4;

__device__ __forceinline__ void async_ld16(void* lds, const void* g) {
    __builtin_amdgcn_global_load_lds(
        (const __attribute__((address_space(1))) unsigned*)g,
        (__attribute__((address_space(3))) unsigned*)lds, 16, 0, 0);
}

__device__ __forceinline__ unsigned short f2bf(float f) {
    unsigned u = __float_as_uint(f);
    u += 0x7FFF + ((u >> 16) & 1);   // round-to-nearest-even (finite inputs)
    return (unsigned short)(u >> 16);
}

// ---------------------------------------------------------------------------
// Pass 0: fp32 -> bf16 conversion (x and Wqk), 4 elements/thread
// ---------------------------------------------------------------------------
__global__ __launch_bounds__(256) void cvt_bf16_kernel(
    const float* __restrict__ src, unsigned short* __restrict__ dst)
{
    int i = blockIdx.x * 256 + threadIdx.x;
    float4 v = ((const float4*)src)[i];
    ushort4 o;
    o.x = f2bf(v.x); o.y = f2bf(v.y); o.z = f2bf(v.z); o.w = f2bf(v.w);
    ((ushort4*)dst)[i] = o;
}

// ---------------------------------------------------------------------------
// Pass 1: qk = x @ W^T + b (bf16 MFMA), fused RoPE + (elu+1) + /softplus(scale)
// m97 structure: 128x128 tile, BK=32, 4 waves (2x2 of 64x64), 16x16x32 MFMA,
// global_load_lds width=16, XOR-swizzled LDS chunks for bank spread.
// ---------------------------------------------------------------------------
#define GBM 128
#define GBN 128
#define GBK 32

__global__ __launch_bounds__(256) void gemm_mfma_kernel(
    const unsigned short* __restrict__ xb,   // (32768,512) bf16
    const unsigned short* __restrict__ Wb,   // (1024,512) bf16
    const float* __restrict__ bqk,           // (1024)
    const float* __restrict__ scale_p,       // (512)
    float* __restrict__ qW,                  // (32768,512)
    float* __restrict__ kW)                  // (32768,512)
{
    __shared__ char lds[16384];
    char* As = lds;            // 128 rows x 32 bf16 (64B/row), chunk-swizzled
    char* Bs = lds + 8192;

    const int t = threadIdx.x;
    const int wave = t >> 6;
    const int lane = t & 63;
    const int quad = lane >> 4;
    const int l16 = lane & 15;

    const int n0 = blockIdx.x * GBN;   // n fastest -> A-tile L2 reuse
    const int m0 = blockIdx.y * GBM;

    const int wm = (wave >> 1) * 64;
    const int wn = (wave & 1) * 64;

    const int srow = t >> 2;    // staging row within 64-row half
    const int sj = t & 3;       // LDS 16B-chunk slot

    f32x4 acc[4][4];
#pragma unroll
    for (int i = 0; i < 4; ++i)
#pragma unroll
        for (int j = 0; j < 4; ++j) acc[i][j] = (f32x4){0.f, 0.f, 0.f, 0.f};

    for (int k0 = 0; k0 < C_DIM; k0 += GBK) {
        __syncthreads();   // previous iter's LDS reads done
#pragma unroll
        for (int p = 0; p < 2; ++p) {
            int m = p * 64 + srow;
            int jp = sj ^ ((m >> 1) & 3);   // global chunk stored at slot sj
            const unsigned short* ga = xb + (size_t)(m0 + m) * C_DIM + k0 + jp * 8;
            async_ld16(As + p * 4096 + wave * 1024, ga);
            const unsigned short* gb = Wb + (size_t)(n0 + m) * C_DIM + k0 + jp * 8;
            async_ld16(Bs + p * 4096 + wave * 1024, gb);
        }
        __syncthreads();   // staging visible (compiler drains vmcnt before barrier)

        bf16x8 a[4], b[4];
        const int swz = (l16 >> 1) & 3;
#pragma unroll
        for (int i = 0; i < 4; ++i) {
            int mr = wm + i * 16 + l16;
            a[i] = *(const bf16x8*)(As + mr * 64 + ((quad ^ swz) * 16));
            int nr = wn + i * 16 + l16;
            b[i] = *(const bf16x8*)(Bs + nr * 64 + ((quad ^ swz) * 16));
        }
#pragma unroll
        for (int i = 0; i < 4; ++i)
#pragma unroll
            for (int j = 0; j < 4; ++j)
                acc[i][j] = __builtin_amdgcn_mfma_f32_16x16x32_bf16(
                    a[i], b[j], acc[i][j], 0, 0, 0);
    }

    // Epilogue: bias + RoPE + elu+1 + /softplus. D[m=quad*4+r][n=l16] per tile.
#pragma unroll
    for (int j = 0; j < 4; ++j) {
        int c = n0 + wn + j * 16 + l16;
        int ch = c & 511;
        float bias = bqk[c];
        float rspv = 1.0f / log1pf(expf(scale_p[ch]));
        int tt = ch >> 1;
        int use_i = (tt < 128);
        float theta = expf((float)(tt & 127) * THETA_COEF);
        float* dst = (c < C_DIM) ? qW : kW;
        int is_im = l16 & 1;
#pragma unroll
        for (int i = 0; i < 4; ++i) {
#pragma unroll
            for (int r = 0; r < 4; ++r) {
                int m = m0 + wm + i * 16 + quad * 4 + r;
                int n = m & (N_TOK - 1);
                float pos = use_i ? (float)(n >> 6) : (float)(n & 63);
                float sv, cv;
                sincosf(pos * theta, &sv, &cv);
                float val = acc[i][j][r] + bias;
                float oth = __shfl_xor(val, 1);   // partner of RoPE pair
                float rot = is_im ? (val * cv + oth * sv) : (val * cv - oth * sv);
                rot = (rot > 0.f) ? (rot + 1.f) : expf(rot);   // elu + 1
                dst[(size_t)m * C_DIM + ch] = rot * rspv;
            }
        }
    }
}

// ---------------------------------------------------------------------------
// Pass 2: per-row norms -> s = ||v|| / ||v^3||  (for q and k)
// ---------------------------------------------------------------------------
__global__ __launch_bounds__(256) void norm_kernel(
    const float* __restrict__ qW, const float* __restrict__ kW,
    float* __restrict__ sq, float* __restrict__ sk)
{
    int wave = threadIdx.x >> 6;
    int lane = threadIdx.x & 63;
    int m = blockIdx.x * 4 + wave;
    const float* qr = qW + (size_t)m * C_DIM;
    const float* kr = kW + (size_t)m * C_DIM;
    float q2 = 0.f, q6 = 0.f, k2 = 0.f, k6 = 0.f;
#pragma unroll
    for (int l = 0; l < 8; ++l) {
        float q = qr[lane + l * 64];
        float k = kr[lane + l * 64];
        float qq = q * q, kk = k * k;
        q2 += qq;
        k2 += kk;
        q6 += qq * qq * qq;
        k6 += kk * kk * kk;
    }
#pragma unroll
    for (int off = 32; off > 0; off >>= 1) {
        q2 += __shfl_down(q2, off);
        q6 += __shfl_down(q6, off);
        k2 += __shfl_down(k2, off);
        k6 += __shfl_down(k6, off);
    }
    if (lane == 0) {
        sq[m] = sqrtf(q2) / sqrtf(q6);
        sk[m] = sqrtf(k2) / sqrtf(k6);
    }
}

// ---------------------------------------------------------------------------
// Pass 3a: partial kv[d][e] = sum_n k_f[n,d]*v[n,e] and km[d] = sum_n k_f[n,d]
// ---------------------------------------------------------------------------
__global__ __launch_bounds__(256) void kv_partial_kernel(
    const float* __restrict__ x, const float* __restrict__ kW,
    const float* __restrict__ sk,
    float* __restrict__ kvp, float* __restrict__ kmp)
{
    int g = blockIdx.x >> 2;       // (b*16+h)
    int split = blockIdx.x & 3;
    int b = g >> 4, h = g & 15;
    int n_start = split * 1024;

    __shared__ float kf[64][36];
    __shared__ float vv[64][36];

    int t = threadIdx.x;
    int col = t & 31, rowb = t >> 5;
    int e = t & 31, d0 = (t >> 5) * 4;
    float acc[4] = {0.f, 0.f, 0.f, 0.f};
    float kmacc = 0.f;

    for (int n0 = n_start; n0 < n_start + 1024; n0 += 64) {
        __syncthreads();
#pragma unroll
        for (int r = 0; r < 8; ++r) {
            int row = r * 8 + rowb;
            int n = n0 + row;
            size_t base = ((size_t)(b * N_TOK + n)) * C_DIM + h * HDIM + col;
            float kvl = kW[base];
            float skv = sk[b * N_TOK + n];
            kf[row][col] = kvl * kvl * kvl * skv;
            vv[row][col] = x[base];
        }
        __syncthreads();
        for (int nn = 0; nn < 64; ++nn) {
            float vval = vv[nn][e];
            float4 k4 = *(const float4*)&kf[nn][d0];
            acc[0] += k4.x * vval;
            acc[1] += k4.y * vval;
            acc[2] += k4.z * vval;
            acc[3] += k4.w * vval;
        }
        if (t < 32) {
            for (int nn = 0; nn < 64; ++nn) kmacc += kf[nn][t];
        }
    }
    size_t pbase = (size_t)blockIdx.x * 1024;
#pragma unroll
    for (int di = 0; di < 4; ++di)
        kvp[pbase + (size_t)(d0 + di) * 32 + e] = acc[di];
    if (t < 32) kmp[blockIdx.x * 32 + t] = kmacc;
}

// Pass 3b: reduce the 4 splits; scale by 1/N
__global__ __launch_bounds__(256) void kv_reduce_kernel(
    const float* __restrict__ kvp, const float* __restrict__ kmp,
    float* __restrict__ kv, float* __restrict__ km)
{
    int g = blockIdx.x;   // 128
    int t = threadIdx.x;
    for (int idx = t; idx < 1024; idx += 256) {
        float s = 0.f;
#pragma unroll
        for (int sp = 0; sp < 4; ++sp)
            s += kvp[((size_t)(g * 4 + sp)) * 1024 + idx];
        kv[(size_t)g * 1024 + idx] = s * (1.0f / 4096.0f);
    }
    if (t < 32) {
        float s = 0.f;
#pragma unroll
        for (int sp = 0; sp < 4; ++sp) s += kmp[(g * 4 + sp) * 32 + t];
        km[g * 32 + t] = s * (1.0f / 4096.0f);
    }
}

// ---------------------------------------------------------------------------
// Pass 4: out[b,n,h*32+e] = z * sum_d q_f[n,d] kv[d,e],  z = 1/(q_f . km + 1e-6)
// ---------------------------------------------------------------------------
__global__ __launch_bounds__(256) void attn_out_kernel(
    const float* __restrict__ qW, const float* __restrict__ sq,
    const float* __restrict__ kv, const float* __restrict__ km,
    float* __restrict__ out)
{
    int g = blockIdx.x;
    int b = g >> 4, h = g & 15;
    int n0 = blockIdx.y * 128;

    __shared__ float kvs[32][33];
    __shared__ float kms[32];
    __shared__ float qf[8][33];

    int t = threadIdx.x;
    for (int idx = t; idx < 1024; idx += 256)
        kvs[idx >> 5][idx & 31] = kv[(size_t)g * 1024 + idx];
    if (t < 32) kms[t] = km[g * 32 + t];
    __syncthreads();

    int e = t & 31, nl = t >> 5;
    for (int chunk = 0; chunk < 128; chunk += 8) {
        int n = n0 + chunk + nl;
        size_t base = ((size_t)(b * N_TOK + n)) * C_DIM + h * HDIM;
        float q = qW[base + e];
        qf[nl][e] = q * q * q * sq[b * N_TOK + n];
        __syncthreads();
        float s1 = 0.f, s2 = 0.f;
#pragma unroll
        for (int d = 0; d < 32; ++d) {
            float qd = qf[nl][d];
            s1 += qd * kvs[d][e];
            s2 += qd * kms[d];
        }
        float z = 1.0f / (s2 + 1e-6f);
        out[base + e] = s1 * z;
        __syncthreads();
    }
}

// ---------------------------------------------------------------------------
// Pass 5: out += depthwise conv5x5(x) + bias
// ---------------------------------------------------------------------------
__global__ __launch_bounds__(256) void conv_kernel(
    const float* __restrict__ x, const float* __restrict__ w,
    const float* __restrict__ bias, float* __restrict__ out)
{
    size_t idx = (size_t)blockIdx.x * 256 + threadIdx.x;
    int c = (int)(idx & 511);
    size_t bn = idx >> 9;
    int n = (int)(bn & (N_TOK - 1));
    int b = (int)(bn >> 12);
    int i = n >> 6, j = n & 63;
    int o = c & 31;
    float accv = bias[o];
#pragma unroll
    for (int ki = 0; ki < 5; ++ki) {
        int ii = i + ki - 2;
        if (ii < 0 || ii >= IMG_H) continue;
#pragma unroll
        for (int kj = 0; kj < 5; ++kj) {
            int jj = j + kj - 2;
            if (jj < 0 || jj >= IMG_W) continue;
            accv += w[o * 25 + ki * 5 + kj] *
                    x[((size_t)(b * N_TOK) + ii * 64 + jj) * C_DIM + c];
        }
    }
    out[idx] += accv;
}

// ---------------------------------------------------------------------------
extern "C" void kernel_launch(void* const* d_in, const int* in_sizes, int n_in,
                              void* d_out, int out_size, void* d_ws, size_t ws_size,
                              hipStream_t stream) {
    const float* x       = (const float*)d_in[0];
    const float* Wqk     = (const float*)d_in[1];
    const float* bqk     = (const float*)d_in[2];
    const float* scale_p = (const float*)d_in[3];
    const float* dwc_w   = (const float*)d_in[4];
    const float* dwc_b   = (const float*)d_in[5];
    float* out = (float*)d_out;
    float* ws = (float*)d_ws;

    // workspace layout (floats): qW | sq | sk | kvp | kmp | kv | km | xb | Wb
    float* qW  = ws;                                  // 16,777,216
    float* sq  = qW + (size_t)M_ROWS * C_DIM;         // 32,768
    float* sk  = sq + M_ROWS;                         // 32,768
    float* kvp = sk + M_ROWS;                         // 524,288
    float* kmp = kvp + 512 * 1024;                    // 16,384
    float* kv  = kmp + 512 * 32;                      // 131,072
    float* km  = kv + 128 * 1024;                     // 2,048
    unsigned short* xb = (unsigned short*)(km + 2048);        // 16.7M bf16 (33.5 MB)
    unsigned short* Wb = xb + (size_t)M_ROWS * C_DIM;         // 1 MB
    float* kW  = out;   // k staged in d_out; consumed before pass 4 overwrites

    cvt_bf16_kernel<<<(M_ROWS * C_DIM) / 1024, 256, 0, stream>>>(x, xb);
    cvt_bf16_kernel<<<(QK_COLS * C_DIM) / 1024, 256, 0, stream>>>(Wqk, Wb);

    dim3 gg(QK_COLS / GBN, M_ROWS / GBM);   // n fastest for A-tile L2 reuse
    gemm_mfma_kernel<<<gg, 256, 0, stream>>>(xb, Wb, bqk, scale_p, qW, kW);

    norm_kernel<<<M_ROWS / 4, 256, 0, stream>>>(qW, kW, sq, sk);

    kv_partial_kernel<<<512, 256, 0, stream>>>(x, kW, sk, kvp, kmp);
    kv_reduce_kernel<<<128, 256, 0, stream>>>(kvp, kmp, kv, km);

    dim3 g4(128, 32);
    attn_out_kernel<<<g4, 256, 0, stream>>>(qW, sq, kv, km, out);

    conv_kernel<<<(M_ROWS * C_DIM) / 256, 256, 0, stream>>>(x, dwc_w, dwc_b, out);
}

// Round 3
// 819.713 us; speedup vs baseline: 1.5846x; 1.4852x over previous
//
#include <hip/hip_runtime.h>
#include <math.h>

// Problem constants (fixed by setup_inputs)
#define B_SZ 8
#define IMG_H 64
#define IMG_W 64
#define N_TOK 4096          // 64*64
#define C_DIM 512
#define HEADS 16
#define HDIM 32
#define M_ROWS (B_SZ * N_TOK)   // 32768
#define QK_COLS (2 * C_DIM)     // 1024

// theta coefficient: -ln(10000)/128
#define THETA_COEF (-0.07195578415606394f)

typedef __attribute__((ext_vector_type(8))) __bf16 bf16x8;
typedef __attribute__((ext_vector_type(4))) float f32x4;

__device__ __forceinline__ void async_ld16(void* lds, const void* g) {
    __builtin_amdgcn_global_load_lds(
        (const __attribute__((address_space(1))) unsigned*)g,
        (__attribute__((address_space(3))) unsigned*)lds, 16, 0, 0);
}

__device__ __forceinline__ unsigned short f2bf(float f) {
    unsigned u = __float_as_uint(f);
    u += 0x7FFF + ((u >> 16) & 1);   // round-to-nearest-even (finite inputs)
    return (unsigned short)(u >> 16);
}

// ---------------------------------------------------------------------------
// Pass 0: fp32 -> bf16 conversion (x and Wqk), 4 elements/thread
// ---------------------------------------------------------------------------
__global__ __launch_bounds__(256) void cvt_bf16_kernel(
    const float* __restrict__ src, unsigned short* __restrict__ dst)
{
    int i = blockIdx.x * 256 + threadIdx.x;
    float4 v = ((const float4*)src)[i];
    ushort4 o;
    o.x = f2bf(v.x); o.y = f2bf(v.y); o.z = f2bf(v.z); o.w = f2bf(v.w);
    ((ushort4*)dst)[i] = o;
}

// ---------------------------------------------------------------------------
// Pass 1: qk = x @ W^T + b (bf16 MFMA), fused RoPE + (elu+1) + /softplus(scale)
// ---------------------------------------------------------------------------
#define GBM 128
#define GBN 128
#define GBK 32

__global__ __launch_bounds__(256) void gemm_mfma_kernel(
    const unsigned short* __restrict__ xb,   // (32768,512) bf16
    const unsigned short* __restrict__ Wb,   // (1024,512) bf16
    const float* __restrict__ bqk,           // (1024)
    const float* __restrict__ scale_p,       // (512)
    float* __restrict__ qW,                  // (32768,512)
    float* __restrict__ kW)                  // (32768,512)
{
    __shared__ char lds[16384];
    char* As = lds;            // 128 rows x 32 bf16 (64B/row), chunk-swizzled
    char* Bs = lds + 8192;

    const int t = threadIdx.x;
    const int wave = t >> 6;
    const int lane = t & 63;
    const int quad = lane >> 4;
    const int l16 = lane & 15;

    const int n0 = blockIdx.x * GBN;   // n fastest -> A-tile L2 reuse
    const int m0 = blockIdx.y * GBM;

    const int wm = (wave >> 1) * 64;
    const int wn = (wave & 1) * 64;

    const int srow = t >> 2;    // staging row within 64-row half
    const int sj = t & 3;       // LDS 16B-chunk slot

    f32x4 acc[4][4];
#pragma unroll
    for (int i = 0; i < 4; ++i)
#pragma unroll
        for (int j = 0; j < 4; ++j) acc[i][j] = (f32x4){0.f, 0.f, 0.f, 0.f};

    for (int k0 = 0; k0 < C_DIM; k0 += GBK) {
        __syncthreads();   // previous iter's LDS reads done
#pragma unroll
        for (int p = 0; p < 2; ++p) {
            int m = p * 64 + srow;
            int jp = sj ^ ((m >> 1) & 3);   // global chunk stored at slot sj
            const unsigned short* ga = xb + (size_t)(m0 + m) * C_DIM + k0 + jp * 8;
            async_ld16(As + p * 4096 + wave * 1024, ga);
            const unsigned short* gb = Wb + (size_t)(n0 + m) * C_DIM + k0 + jp * 8;
            async_ld16(Bs + p * 4096 + wave * 1024, gb);
        }
        __syncthreads();   // staging visible

        bf16x8 a[4], b[4];
        const int swz = (l16 >> 1) & 3;
#pragma unroll
        for (int i = 0; i < 4; ++i) {
            int mr = wm + i * 16 + l16;
            a[i] = *(const bf16x8*)(As + mr * 64 + ((quad ^ swz) * 16));
            int nr = wn + i * 16 + l16;
            b[i] = *(const bf16x8*)(Bs + nr * 64 + ((quad ^ swz) * 16));
        }
#pragma unroll
        for (int i = 0; i < 4; ++i)
#pragma unroll
            for (int j = 0; j < 4; ++j)
                acc[i][j] = __builtin_amdgcn_mfma_f32_16x16x32_bf16(
                    a[i], b[j], acc[i][j], 0, 0, 0);
    }

    // Epilogue: bias + RoPE + elu+1 + /softplus. D[m=quad*4+r][n=l16] per tile.
#pragma unroll
    for (int j = 0; j < 4; ++j) {
        int c = n0 + wn + j * 16 + l16;
        int ch = c & 511;
        float bias = bqk[c];
        float rspv = 1.0f / log1pf(expf(scale_p[ch]));
        int tt = ch >> 1;
        int use_i = (tt < 128);
        float theta = expf((float)(tt & 127) * THETA_COEF);
        float* dst = (c < C_DIM) ? qW : kW;
        int is_im = l16 & 1;
#pragma unroll
        for (int i = 0; i < 4; ++i) {
#pragma unroll
            for (int r = 0; r < 4; ++r) {
                int m = m0 + wm + i * 16 + quad * 4 + r;
                int n = m & (N_TOK - 1);
                float pos = use_i ? (float)(n >> 6) : (float)(n & 63);
                float sv, cv;
                sincosf(pos * theta, &sv, &cv);
                float val = acc[i][j][r] + bias;
                float oth = __shfl_xor(val, 1);   // partner of RoPE pair
                float rot = is_im ? (val * cv + oth * sv) : (val * cv - oth * sv);
                rot = (rot > 0.f) ? (rot + 1.f) : expf(rot);   // elu + 1
                dst[(size_t)m * C_DIM + ch] = rot * rspv;
            }
        }
    }
}

// ---------------------------------------------------------------------------
// Pass 2: per-row norms -> s = ||v|| / ||v^3||  (for q and k)
// ---------------------------------------------------------------------------
__global__ __launch_bounds__(256) void norm_kernel(
    const float* __restrict__ qW, const float* __restrict__ kW,
    float* __restrict__ sq, float* __restrict__ sk)
{
    int wave = threadIdx.x >> 6;
    int lane = threadIdx.x & 63;
    int m = blockIdx.x * 4 + wave;
    const float* qr = qW + (size_t)m * C_DIM;
    const float* kr = kW + (size_t)m * C_DIM;
    float q2 = 0.f, q6 = 0.f, k2 = 0.f, k6 = 0.f;
#pragma unroll
    for (int l = 0; l < 8; ++l) {
        float q = qr[lane + l * 64];
        float k = kr[lane + l * 64];
        float qq = q * q, kk = k * k;
        q2 += qq;
        k2 += kk;
        q6 += qq * qq * qq;
        k6 += kk * kk * kk;
    }
#pragma unroll
    for (int off = 32; off > 0; off >>= 1) {
        q2 += __shfl_down(q2, off);
        q6 += __shfl_down(q6, off);
        k2 += __shfl_down(k2, off);
        k6 += __shfl_down(k6, off);
    }
    if (lane == 0) {
        sq[m] = sqrtf(q2) / sqrtf(q6);
        sk[m] = sqrtf(k2) / sqrtf(k6);
    }
}

// ---------------------------------------------------------------------------
// Pass 3a: partial kv[d][e] = sum_n k_f[n,d]*v[n,e] and km[d] = sum_n k_f[n,d]
// ---------------------------------------------------------------------------
__global__ __launch_bounds__(256) void kv_partial_kernel(
    const float* __restrict__ x, const float* __restrict__ kW,
    const float* __restrict__ sk,
    float* __restrict__ kvp, float* __restrict__ kmp)
{
    int g = blockIdx.x >> 2;       // (b*16+h)
    int split = blockIdx.x & 3;
    int b = g >> 4, h = g & 15;
    int n_start = split * 1024;

    __shared__ float kf[64][36];
    __shared__ float vv[64][36];

    int t = threadIdx.x;
    int col = t & 31, rowb = t >> 5;
    int e = t & 31, d0 = (t >> 5) * 4;
    float acc[4] = {0.f, 0.f, 0.f, 0.f};
    float kmacc = 0.f;

    for (int n0 = n_start; n0 < n_start + 1024; n0 += 64) {
        __syncthreads();
#pragma unroll
        for (int r = 0; r < 8; ++r) {
            int row = r * 8 + rowb;
            int n = n0 + row;
            size_t base = ((size_t)(b * N_TOK + n)) * C_DIM + h * HDIM + col;
            float kvl = kW[base];
            float skv = sk[b * N_TOK + n];
            kf[row][col] = kvl * kvl * kvl * skv;
            vv[row][col] = x[base];
        }
        __syncthreads();
        for (int nn = 0; nn < 64; ++nn) {
            float vval = vv[nn][e];
            float4 k4 = *(const float4*)&kf[nn][d0];
            acc[0] += k4.x * vval;
            acc[1] += k4.y * vval;
            acc[2] += k4.z * vval;
            acc[3] += k4.w * vval;
        }
        if (t < 32) {
            for (int nn = 0; nn < 64; ++nn) kmacc += kf[nn][t];
        }
    }
    size_t pbase = (size_t)blockIdx.x * 1024;
#pragma unroll
    for (int di = 0; di < 4; ++di)
        kvp[pbase + (size_t)(d0 + di) * 32 + e] = acc[di];
    if (t < 32) kmp[blockIdx.x * 32 + t] = kmacc;
}

// Pass 3b: reduce the 4 splits; scale by 1/N
__global__ __launch_bounds__(256) void kv_reduce_kernel(
    const float* __restrict__ kvp, const float* __restrict__ kmp,
    float* __restrict__ kv, float* __restrict__ km)
{
    int g = blockIdx.x;   // 128
    int t = threadIdx.x;
    for (int idx = t; idx < 1024; idx += 256) {
        float s = 0.f;
#pragma unroll
        for (int sp = 0; sp < 4; ++sp)
            s += kvp[((size_t)(g * 4 + sp)) * 1024 + idx];
        kv[(size_t)g * 1024 + idx] = s * (1.0f / 4096.0f);
    }
    if (t < 32) {
        float s = 0.f;
#pragma unroll
        for (int sp = 0; sp < 4; ++sp) s += kmp[(g * 4 + sp) * 32 + t];
        km[g * 32 + t] = s * (1.0f / 4096.0f);
    }
}

// ---------------------------------------------------------------------------
// Pass 4: out[b,n,h*32+e] = z * sum_d q_f[n,d] kv[d,e],  z = 1/(q_f . km + 1e-6)
// ---------------------------------------------------------------------------
__global__ __launch_bounds__(256) void attn_out_kernel(
    const float* __restrict__ qW, const float* __restrict__ sq,
    const float* __restrict__ kv, const float* __restrict__ km,
    float* __restrict__ out)
{
    int g = blockIdx.x;
    int b = g >> 4, h = g & 15;
    int n0 = blockIdx.y * 128;

    __shared__ float kvs[32][33];
    __shared__ float kms[32];
    __shared__ float qf[8][33];

    int t = threadIdx.x;
    for (int idx = t; idx < 1024; idx += 256)
        kvs[idx >> 5][idx & 31] = kv[(size_t)g * 1024 + idx];
    if (t < 32) kms[t] = km[g * 32 + t];
    __syncthreads();

    int e = t & 31, nl = t >> 5;
    for (int chunk = 0; chunk < 128; chunk += 8) {
        int n = n0 + chunk + nl;
        size_t base = ((size_t)(b * N_TOK + n)) * C_DIM + h * HDIM;
        float q = qW[base + e];
        qf[nl][e] = q * q * q * sq[b * N_TOK + n];
        __syncthreads();
        float s1 = 0.f, s2 = 0.f;
#pragma unroll
        for (int d = 0; d < 32; ++d) {
            float qd = qf[nl][d];
            s1 += qd * kvs[d][e];
            s2 += qd * kms[d];
        }
        float z = 1.0f / (s2 + 1e-6f);
        out[base + e] = s1 * z;
        __syncthreads();
    }
}

// ---------------------------------------------------------------------------
// Pass 5: out += depthwise conv5x5(x) + bias
// Register-blocked: each thread = 4 j-positions x 4 channels (float4).
// 8 independent float4 loads in flight per row -> MLP instead of latency-bound.
// ---------------------------------------------------------------------------
__global__ __launch_bounds__(256) void conv_kernel(
    const float* __restrict__ x, const float* __restrict__ w,
    const float* __restrict__ bias, float* __restrict__ out)
{
    __shared__ float wl[25][32];
    int t = threadIdx.x;
    for (int idx = t; idx < 800; idx += 256) {
        int o = idx & 31, tap = idx >> 5;
        wl[tap][o] = w[o * 25 + tap];
    }
    __syncthreads();

    int bi = blockIdx.x >> 3;        // b*64 + i
    int part = blockIdx.x & 7;
    int b = bi >> 6, i = bi & 63;
    int jg = part * 2 + (t >> 7);    // j-group of 4
    int cg = t & 127;                // channel group of 4
    int j0 = jg * 4;
    int o4 = (cg & 7) * 4;           // kernel-channel base (c%32)

    const float* xbase = x + ((size_t)b * N_TOK) * C_DIM + cg * 4;

    float4 b4 = *(const float4*)&bias[o4];
    float4 acc[4] = {b4, b4, b4, b4};

#pragma unroll
    for (int ki = 0; ki < 5; ++ki) {
        int ii = i + ki - 2;
        if (ii < 0 || ii >= IMG_H) continue;      // wave-uniform
        const float* xr = xbase + (size_t)ii * 64 * C_DIM;
        float4 row[8];
#pragma unroll
        for (int jx = 0; jx < 8; ++jx) {
            int jj = j0 + jx - 2;
            row[jx] = (jj >= 0 && jj < IMG_W)
                          ? *(const float4*)(xr + (size_t)jj * C_DIM)
                          : make_float4(0.f, 0.f, 0.f, 0.f);
        }
#pragma unroll
        for (int kj = 0; kj < 5; ++kj) {
            float4 w4 = *(const float4*)&wl[ki * 5 + kj][o4];
#pragma unroll
            for (int jo = 0; jo < 4; ++jo) {
                acc[jo].x += w4.x * row[jo + kj].x;
                acc[jo].y += w4.y * row[jo + kj].y;
                acc[jo].z += w4.z * row[jo + kj].z;
                acc[jo].w += w4.w * row[jo + kj].w;
            }
        }
    }

    float* op = out + ((size_t)(b * N_TOK + i * 64 + j0)) * C_DIM + cg * 4;
#pragma unroll
    for (int jo = 0; jo < 4; ++jo) {
        float4 cur = *(float4*)(op + (size_t)jo * C_DIM);
        cur.x += acc[jo].x;
        cur.y += acc[jo].y;
        cur.z += acc[jo].z;
        cur.w += acc[jo].w;
        *(float4*)(op + (size_t)jo * C_DIM) = cur;
    }
}

// ---------------------------------------------------------------------------
extern "C" void kernel_launch(void* const* d_in, const int* in_sizes, int n_in,
                              void* d_out, int out_size, void* d_ws, size_t ws_size,
                              hipStream_t stream) {
    const float* x       = (const float*)d_in[0];
    const float* Wqk     = (const float*)d_in[1];
    const float* bqk     = (const float*)d_in[2];
    const float* scale_p = (const float*)d_in[3];
    const float* dwc_w   = (const float*)d_in[4];
    const float* dwc_b   = (const float*)d_in[5];
    float* out = (float*)d_out;
    float* ws = (float*)d_ws;

    // workspace layout (floats): qW | sq | sk | kvp | kmp | kv | km | xb | Wb
    float* qW  = ws;                                  // 16,777,216
    float* sq  = qW + (size_t)M_ROWS * C_DIM;         // 32,768
    float* sk  = sq + M_ROWS;                         // 32,768
    float* kvp = sk + M_ROWS;                         // 524,288
    float* kmp = kvp + 512 * 1024;                    // 16,384
    float* kv  = kmp + 512 * 32;                      // 131,072
    float* km  = kv + 128 * 1024;                     // 2,048
    unsigned short* xb = (unsigned short*)(km + 2048);        // bf16 x
    unsigned short* Wb = xb + (size_t)M_ROWS * C_DIM;         // bf16 W
    float* kW  = out;   // k staged in d_out; consumed before pass 4 overwrites

    cvt_bf16_kernel<<<(M_ROWS * C_DIM) / 1024, 256, 0, stream>>>(x, xb);
    cvt_bf16_kernel<<<(QK_COLS * C_DIM) / 1024, 256, 0, stream>>>(Wqk, Wb);

    dim3 gg(QK_COLS / GBN, M_ROWS / GBM);
    gemm_mfma_kernel<<<gg, 256, 0, stream>>>(xb, Wb, bqk, scale_p, qW, kW);

    norm_kernel<<<M_ROWS / 4, 256, 0, stream>>>(qW, kW, sq, sk);

    kv_partial_kernel<<<512, 256, 0, stream>>>(x, kW, sk, kvp, kmp);
    kv_reduce_kernel<<<128, 256, 0, stream>>>(kvp, kmp, kv, km);

    dim3 g4(128, 32);
    attn_out_kernel<<<g4, 256, 0, stream>>>(qW, sq, kv, km, out);

    conv_kernel<<<M_ROWS / 8, 256, 0, stream>>>(x, dwc_w, dwc_b, out);
}

// Round 4
// 776.662 us; speedup vs baseline: 1.6725x; 1.0554x over previous
//
#include <hip/hip_runtime.h>
#include <math.h>

// Problem constants (fixed by setup_inputs)
#define B_SZ 8
#define IMG_H 64
#define IMG_W 64
#define N_TOK 4096          // 64*64
#define C_DIM 512
#define HEADS 16
#define HDIM 32
#define M_ROWS (B_SZ * N_TOK)   // 32768
#define QK_COLS (2 * C_DIM)     // 1024

// theta coefficient: -ln(10000)/128
#define THETA_COEF (-0.07195578415606394f)

typedef __attribute__((ext_vector_type(8))) __bf16 bf16x8;
typedef __attribute__((ext_vector_type(4))) float f32x4;

__device__ __forceinline__ void async_ld16(void* lds, const void* g) {
    __builtin_amdgcn_global_load_lds(
        (const __attribute__((address_space(1))) unsigned*)g,
        (__attribute__((address_space(3))) unsigned*)lds, 16, 0, 0);
}

__device__ __forceinline__ unsigned short f2bf(float f) {
    unsigned u = __float_as_uint(f);
    u += 0x7FFF + ((u >> 16) & 1);   // round-to-nearest-even (finite inputs)
    return (unsigned short)(u >> 16);
}

// ---------------------------------------------------------------------------
// Pass 0: fp32 -> bf16 conversion (x and Wqk), 4 elements/thread
// ---------------------------------------------------------------------------
__global__ __launch_bounds__(256) void cvt_bf16_kernel(
    const float* __restrict__ src, unsigned short* __restrict__ dst)
{
    int i = blockIdx.x * 256 + threadIdx.x;
    float4 v = ((const float4*)src)[i];
    ushort4 o;
    o.x = f2bf(v.x); o.y = f2bf(v.y); o.z = f2bf(v.z); o.w = f2bf(v.w);
    ((ushort4*)dst)[i] = o;
}

// ---------------------------------------------------------------------------
// Pass 1: qk = x @ W^T + b (bf16 MFMA), fused RoPE + (elu+1) + /softplus(scale)
// __launch_bounds__(256,2): VGPR cap 256 -> NO accumulator spill (round-3 bug:
// default bounds capped at 84 VGPR, spilled acc to scratch = 2.3 GB HBM writes)
// XCD swizzle: each XCD owns a 32-row band of m-tiles so its A working set
// (~1 MB) stays L2-resident instead of every A-tile being fetched by 8 XCDs.
// ---------------------------------------------------------------------------
#define GBM 128
#define GBN 128
#define GBK 32

__global__ __launch_bounds__(256, 2) void gemm_mfma_kernel(
    const unsigned short* __restrict__ xb,   // (32768,512) bf16
    const unsigned short* __restrict__ Wb,   // (1024,512) bf16
    const float* __restrict__ bqk,           // (1024)
    const float* __restrict__ scale_p,       // (512)
    float* __restrict__ qW,                  // (32768,512)
    float* __restrict__ kW)                  // (32768,512)
{
    __shared__ char lds[16384];
    char* As = lds;            // 128 rows x 32 bf16 (64B/row), chunk-swizzled
    char* Bs = lds + 8192;

    const int t = threadIdx.x;
    const int wave = t >> 6;
    const int lane = t & 63;
    const int quad = lane >> 4;
    const int l16 = lane & 15;

    // XCD-aware swizzle: flat = bx + 8*by; xcd = flat&7 (round-robin);
    // give each xcd all 8 n-tiles of 32 consecutive m-tiles.
    const int flat = blockIdx.x + 8 * blockIdx.y;
    const int xcd = flat & 7;
    const int ii_ = flat >> 3;
    const int n0 = (ii_ & 7) * GBN;
    const int m0 = (xcd * 32 + (ii_ >> 3)) * GBM;

    const int wm = (wave >> 1) * 64;
    const int wn = (wave & 1) * 64;

    const int srow = t >> 2;    // staging row within 64-row half
    const int sj = t & 3;       // LDS 16B-chunk slot

    f32x4 acc[4][4];
#pragma unroll
    for (int i = 0; i < 4; ++i)
#pragma unroll
        for (int j = 0; j < 4; ++j) acc[i][j] = (f32x4){0.f, 0.f, 0.f, 0.f};

    for (int k0 = 0; k0 < C_DIM; k0 += GBK) {
        __syncthreads();   // previous iter's LDS reads done
#pragma unroll
        for (int p = 0; p < 2; ++p) {
            int m = p * 64 + srow;
            int jp = sj ^ ((m >> 1) & 3);   // global chunk stored at slot sj
            const unsigned short* ga = xb + (size_t)(m0 + m) * C_DIM + k0 + jp * 8;
            async_ld16(As + p * 4096 + wave * 1024, ga);
            const unsigned short* gb = Wb + (size_t)(n0 + m) * C_DIM + k0 + jp * 8;
            async_ld16(Bs + p * 4096 + wave * 1024, gb);
        }
        __syncthreads();   // staging visible

        bf16x8 a[4], b[4];
        const int swz = (l16 >> 1) & 3;
#pragma unroll
        for (int i = 0; i < 4; ++i) {
            int mr = wm + i * 16 + l16;
            a[i] = *(const bf16x8*)(As + mr * 64 + ((quad ^ swz) * 16));
            int nr = wn + i * 16 + l16;
            b[i] = *(const bf16x8*)(Bs + nr * 64 + ((quad ^ swz) * 16));
        }
#pragma unroll
        for (int i = 0; i < 4; ++i)
#pragma unroll
            for (int j = 0; j < 4; ++j)
                acc[i][j] = __builtin_amdgcn_mfma_f32_16x16x32_bf16(
                    a[i], b[j], acc[i][j], 0, 0, 0);
    }

    // Epilogue: bias + RoPE + elu+1 + /softplus. D[m=quad*4+r][n=l16] per tile.
#pragma unroll
    for (int j = 0; j < 4; ++j) {
        int c = n0 + wn + j * 16 + l16;
        int ch = c & 511;
        float bias = bqk[c];
        float rspv = 1.0f / log1pf(expf(scale_p[ch]));
        int tt = ch >> 1;
        int use_i = (tt < 128);
        float theta = expf((float)(tt & 127) * THETA_COEF);
        float* dst = (c < C_DIM) ? qW : kW;
        int is_im = l16 & 1;
#pragma unroll
        for (int i = 0; i < 4; ++i) {
#pragma unroll
            for (int r = 0; r < 4; ++r) {
                int m = m0 + wm + i * 16 + quad * 4 + r;
                int n = m & (N_TOK - 1);
                float pos = use_i ? (float)(n >> 6) : (float)(n & 63);
                float sv, cv;
                sincosf(pos * theta, &sv, &cv);
                float val = acc[i][j][r] + bias;
                float oth = __shfl_xor(val, 1);   // partner of RoPE pair
                float rot = is_im ? (val * cv + oth * sv) : (val * cv - oth * sv);
                rot = (rot > 0.f) ? (rot + 1.f) : expf(rot);   // elu + 1
                dst[(size_t)m * C_DIM + ch] = rot * rspv;
            }
        }
    }
}

// ---------------------------------------------------------------------------
// Pass 2: per-row norms -> s = ||v|| / ||v^3||  (for q and k)
// ---------------------------------------------------------------------------
__global__ __launch_bounds__(256) void norm_kernel(
    const float* __restrict__ qW, const float* __restrict__ kW,
    float* __restrict__ sq, float* __restrict__ sk)
{
    int wave = threadIdx.x >> 6;
    int lane = threadIdx.x & 63;
    int m = blockIdx.x * 4 + wave;
    const float* qr = qW + (size_t)m * C_DIM;
    const float* kr = kW + (size_t)m * C_DIM;
    float q2 = 0.f, q6 = 0.f, k2 = 0.f, k6 = 0.f;
#pragma unroll
    for (int l = 0; l < 8; ++l) {
        float q = qr[lane + l * 64];
        float k = kr[lane + l * 64];
        float qq = q * q, kk = k * k;
        q2 += qq;
        k2 += kk;
        q6 += qq * qq * qq;
        k6 += kk * kk * kk;
    }
#pragma unroll
    for (int off = 32; off > 0; off >>= 1) {
        q2 += __shfl_down(q2, off);
        q6 += __shfl_down(q6, off);
        k2 += __shfl_down(k2, off);
        k6 += __shfl_down(k6, off);
    }
    if (lane == 0) {
        sq[m] = sqrtf(q2) / sqrtf(q6);
        sk[m] = sqrtf(k2) / sqrtf(k6);
    }
}

// ---------------------------------------------------------------------------
// Pass 3a: partial kv[d][e] = sum_n k_f[n,d]*v[n,e] and km[d] = sum_n k_f[n,d]
// ---------------------------------------------------------------------------
__global__ __launch_bounds__(256) void kv_partial_kernel(
    const float* __restrict__ x, const float* __restrict__ kW,
    const float* __restrict__ sk,
    float* __restrict__ kvp, float* __restrict__ kmp)
{
    int g = blockIdx.x >> 2;       // (b*16+h)
    int split = blockIdx.x & 3;
    int b = g >> 4, h = g & 15;
    int n_start = split * 1024;

    __shared__ float kf[64][36];
    __shared__ float vv[64][36];

    int t = threadIdx.x;
    int col = t & 31, rowb = t >> 5;
    int e = t & 31, d0 = (t >> 5) * 4;
    float acc[4] = {0.f, 0.f, 0.f, 0.f};
    float kmacc = 0.f;

    for (int n0 = n_start; n0 < n_start + 1024; n0 += 64) {
        __syncthreads();
#pragma unroll
        for (int r = 0; r < 8; ++r) {
            int row = r * 8 + rowb;
            int n = n0 + row;
            size_t base = ((size_t)(b * N_TOK + n)) * C_DIM + h * HDIM + col;
            float kvl = kW[base];
            float skv = sk[b * N_TOK + n];
            kf[row][col] = kvl * kvl * kvl * skv;
            vv[row][col] = x[base];
        }
        __syncthreads();
        for (int nn = 0; nn < 64; ++nn) {
            float vval = vv[nn][e];
            float4 k4 = *(const float4*)&kf[nn][d0];
            acc[0] += k4.x * vval;
            acc[1] += k4.y * vval;
            acc[2] += k4.z * vval;
            acc[3] += k4.w * vval;
        }
        if (t < 32) {
            for (int nn = 0; nn < 64; ++nn) kmacc += kf[nn][t];
        }
    }
    size_t pbase = (size_t)blockIdx.x * 1024;
#pragma unroll
    for (int di = 0; di < 4; ++di)
        kvp[pbase + (size_t)(d0 + di) * 32 + e] = acc[di];
    if (t < 32) kmp[blockIdx.x * 32 + t] = kmacc;
}

// Pass 3b: reduce the 4 splits; scale by 1/N
__global__ __launch_bounds__(256) void kv_reduce_kernel(
    const float* __restrict__ kvp, const float* __restrict__ kmp,
    float* __restrict__ kv, float* __restrict__ km)
{
    int g = blockIdx.x;   // 128
    int t = threadIdx.x;
    for (int idx = t; idx < 1024; idx += 256) {
        float s = 0.f;
#pragma unroll
        for (int sp = 0; sp < 4; ++sp)
            s += kvp[((size_t)(g * 4 + sp)) * 1024 + idx];
        kv[(size_t)g * 1024 + idx] = s * (1.0f / 4096.0f);
    }
    if (t < 32) {
        float s = 0.f;
#pragma unroll
        for (int sp = 0; sp < 4; ++sp) s += kmp[(g * 4 + sp) * 32 + t];
        km[g * 32 + t] = s * (1.0f / 4096.0f);
    }
}

// ---------------------------------------------------------------------------
// Pass 4: out[b,n,h*32+e] = z * sum_d q_f[n,d] kv[d,e],  z = 1/(q_f . km + 1e-6)
// ---------------------------------------------------------------------------
__global__ __launch_bounds__(256) void attn_out_kernel(
    const float* __restrict__ qW, const float* __restrict__ sq,
    const float* __restrict__ kv, const float* __restrict__ km,
    float* __restrict__ out)
{
    int g = blockIdx.x;
    int b = g >> 4, h = g & 15;
    int n0 = blockIdx.y * 128;

    __shared__ float kvs[32][33];
    __shared__ float kms[32];
    __shared__ float qf[8][33];

    int t = threadIdx.x;
    for (int idx = t; idx < 1024; idx += 256)
        kvs[idx >> 5][idx & 31] = kv[(size_t)g * 1024 + idx];
    if (t < 32) kms[t] = km[g * 32 + t];
    __syncthreads();

    int e = t & 31, nl = t >> 5;
    for (int chunk = 0; chunk < 128; chunk += 8) {
        int n = n0 + chunk + nl;
        size_t base = ((size_t)(b * N_TOK + n)) * C_DIM + h * HDIM;
        float q = qW[base + e];
        qf[nl][e] = q * q * q * sq[b * N_TOK + n];
        __syncthreads();
        float s1 = 0.f, s2 = 0.f;
#pragma unroll
        for (int d = 0; d < 32; ++d) {
            float qd = qf[nl][d];
            s1 += qd * kvs[d][e];
            s2 += qd * kms[d];
        }
        float z = 1.0f / (s2 + 1e-6f);
        out[base + e] = s1 * z;
        __syncthreads();
    }
}

// ---------------------------------------------------------------------------
// Pass 5: out += depthwise conv5x5(x) + bias
// Register-blocked: each thread = 4 j-positions x 4 channels (float4).
// (256,2): keep VGPR cap high enough for row[8]+acc[4] live float4s.
// ---------------------------------------------------------------------------
__global__ __launch_bounds__(256, 2) void conv_kernel(
    const float* __restrict__ x, const float* __restrict__ w,
    const float* __restrict__ bias, float* __restrict__ out)
{
    __shared__ float wl[25][32];
    int t = threadIdx.x;
    for (int idx = t; idx < 800; idx += 256) {
        int o = idx & 31, tap = idx >> 5;
        wl[tap][o] = w[o * 25 + tap];
    }
    __syncthreads();

    int bi = blockIdx.x >> 3;        // b*64 + i
    int part = blockIdx.x & 7;
    int b = bi >> 6, i = bi & 63;
    int jg = part * 2 + (t >> 7);    // j-group of 4
    int cg = t & 127;                // channel group of 4
    int j0 = jg * 4;
    int o4 = (cg & 7) * 4;           // kernel-channel base (c%32)

    const float* xbase = x + ((size_t)b * N_TOK) * C_DIM + cg * 4;

    float4 b4 = *(const float4*)&bias[o4];
    float4 acc[4] = {b4, b4, b4, b4};

#pragma unroll
    for (int ki = 0; ki < 5; ++ki) {
        int ii = i + ki - 2;
        if (ii < 0 || ii >= IMG_H) continue;      // wave-uniform
        const float* xr = xbase + (size_t)ii * 64 * C_DIM;
        float4 row[8];
#pragma unroll
        for (int jx = 0; jx < 8; ++jx) {
            int jj = j0 + jx - 2;
            row[jx] = (jj >= 0 && jj < IMG_W)
                          ? *(const float4*)(xr + (size_t)jj * C_DIM)
                          : make_float4(0.f, 0.f, 0.f, 0.f);
        }
#pragma unroll
        for (int kj = 0; kj < 5; ++kj) {
            float4 w4 = *(const float4*)&wl[ki * 5 + kj][o4];
#pragma unroll
            for (int jo = 0; jo < 4; ++jo) {
                acc[jo].x += w4.x * row[jo + kj].x;
                acc[jo].y += w4.y * row[jo + kj].y;
                acc[jo].z += w4.z * row[jo + kj].z;
                acc[jo].w += w4.w * row[jo + kj].w;
            }
        }
    }

    float* op = out + ((size_t)(b * N_TOK + i * 64 + j0)) * C_DIM + cg * 4;
#pragma unroll
    for (int jo = 0; jo < 4; ++jo) {
        float4 cur = *(float4*)(op + (size_t)jo * C_DIM);
        cur.x += acc[jo].x;
        cur.y += acc[jo].y;
        cur.z += acc[jo].z;
        cur.w += acc[jo].w;
        *(float4*)(op + (size_t)jo * C_DIM) = cur;
    }
}

// ---------------------------------------------------------------------------
extern "C" void kernel_launch(void* const* d_in, const int* in_sizes, int n_in,
                              void* d_out, int out_size, void* d_ws, size_t ws_size,
                              hipStream_t stream) {
    const float* x       = (const float*)d_in[0];
    const float* Wqk     = (const float*)d_in[1];
    const float* bqk     = (const float*)d_in[2];
    const float* scale_p = (const float*)d_in[3];
    const float* dwc_w   = (const float*)d_in[4];
    const float* dwc_b   = (const float*)d_in[5];
    float* out = (float*)d_out;
    float* ws = (float*)d_ws;

    // workspace layout (floats): qW | sq | sk | kvp | kmp | kv | km | xb | Wb
    float* qW  = ws;                                  // 16,777,216
    float* sq  = qW + (size_t)M_ROWS * C_DIM;         // 32,768
    float* sk  = sq + M_ROWS;                         // 32,768
    float* kvp = sk + M_ROWS;                         // 524,288
    float* kmp = kvp + 512 * 1024;                    // 16,384
    float* kv  = kmp + 512 * 32;                      // 131,072
    float* km  = kv + 128 * 1024;                     // 2,048
    unsigned short* xb = (unsigned short*)(km + 2048);        // bf16 x
    unsigned short* Wb = xb + (size_t)M_ROWS * C_DIM;         // bf16 W
    float* kW  = out;   // k staged in d_out; consumed before pass 4 overwrites

    cvt_bf16_kernel<<<(M_ROWS * C_DIM) / 1024, 256, 0, stream>>>(x, xb);
    cvt_bf16_kernel<<<(QK_COLS * C_DIM) / 1024, 256, 0, stream>>>(Wqk, Wb);

    dim3 gg(QK_COLS / GBN, M_ROWS / GBM);
    gemm_mfma_kernel<<<gg, 256, 0, stream>>>(xb, Wb, bqk, scale_p, qW, kW);

    norm_kernel<<<M_ROWS / 4, 256, 0, stream>>>(qW, kW, sq, sk);

    kv_partial_kernel<<<512, 256, 0, stream>>>(x, kW, sk, kvp, kmp);
    kv_reduce_kernel<<<128, 256, 0, stream>>>(kvp, kmp, kv, km);

    dim3 g4(128, 32);
    attn_out_kernel<<<g4, 256, 0, stream>>>(qW, sq, kv, km, out);

    conv_kernel<<<M_ROWS / 8, 256, 0, stream>>>(x, dwc_w, dwc_b, out);
}

// Round 6
// 484.809 us; speedup vs baseline: 2.6793x; 1.6020x over previous
//
#include <hip/hip_runtime.h>
#include <math.h>

// Problem constants (fixed by setup_inputs)
#define B_SZ 8
#define IMG_H 64
#define IMG_W 64
#define N_TOK 4096          // 64*64
#define C_DIM 512
#define HEADS 16
#define HDIM 32
#define M_ROWS (B_SZ * N_TOK)   // 32768
#define QK_COLS (2 * C_DIM)     // 1024

// theta coefficient: -ln(10000)/128
#define THETA_COEF (-0.07195578415606394f)

typedef __attribute__((ext_vector_type(8))) __bf16 bf16x8;
typedef __attribute__((ext_vector_type(4))) float f32x4;

__device__ __forceinline__ void async_ld16(void* lds, const void* g) {
    __builtin_amdgcn_global_load_lds(
        (const __attribute__((address_space(1))) unsigned*)g,
        (__attribute__((address_space(3))) unsigned*)lds, 16, 0, 0);
}

__device__ __forceinline__ unsigned short f2bf(float f) {
    unsigned u = __float_as_uint(f);
    u += 0x7FFF + ((u >> 16) & 1);   // round-to-nearest-even (finite inputs)
    return (unsigned short)(u >> 16);
}

// ---------------------------------------------------------------------------
// Pass 0a: fp32 -> bf16 conversion (x and Wqk), 4 elements/thread
// ---------------------------------------------------------------------------
__global__ __launch_bounds__(256) void cvt_bf16_kernel(
    const float* __restrict__ src, unsigned short* __restrict__ dst)
{
    int i = blockIdx.x * 256 + threadIdx.x;
    float4 v = ((const float4*)src)[i];
    ushort4 o;
    o.x = f2bf(v.x); o.y = f2bf(v.y); o.z = f2bf(v.z); o.w = f2bf(v.w);
    ((ushort4*)dst)[i] = o;
}

// ---------------------------------------------------------------------------
// Pass 0b: RoPE cos/sin LUT: lut[pos*128+t] = cos(pos*theta_t), +8192 = sin.
// Removes sincosf (pointer-writing libm -> scratch slots) from the GEMM epilogue.
// ---------------------------------------------------------------------------
__global__ __launch_bounds__(256) void rope_lut_kernel(float* __restrict__ lut)
{
    int idx = blockIdx.x * 256 + threadIdx.x;   // 8192
    int pos = idx >> 7, tt = idx & 127;
    float theta = expf((float)tt * THETA_COEF);
    float ang = (float)pos * theta;
    lut[idx] = cosf(ang);
    lut[idx + 8192] = sinf(ang);
}

// ---------------------------------------------------------------------------
// Pass 1: qk = x @ W^T + b (bf16 MFMA), fused RoPE + (elu+1) + /softplus(scale)
// Named accumulators (no array -> no scratch; round-4 bug: acc[4][4] pinned to
// scratch, 16 k-iters x 256 B/thread = 2.1 GB of HBM writebacks).
// ---------------------------------------------------------------------------
#define GBM 128
#define GBN 128
#define GBK 32

#define EPI_I(I, ACC) do {                                                    \
    _Pragma("unroll")                                                         \
    for (int r = 0; r < 4; ++r) {                                             \
        int m = m0 + wm + (I) * 16 + quad * 4 + r;                            \
        int n = m & (N_TOK - 1);                                              \
        int pos = use_i ? (n >> 6) : (n & 63);                                \
        float cv = lbase[pos * 128];                                          \
        float sv = lbase[pos * 128 + 8192];                                   \
        float val = (ACC)[r] + bias;                                          \
        float oth = __shfl_xor(val, 1);                                       \
        float rot = is_im ? (val * cv + oth * sv) : (val * cv - oth * sv);    \
        rot = (rot > 0.f) ? (rot + 1.f) : expf(rot);                          \
        dst[(size_t)m * C_DIM + ch] = rot * rspv;                             \
    }                                                                         \
} while (0)

#define EPI_J(J, A0, A1, A2, A3) do {                                         \
    int c = n0 + wn + (J) * 16 + l16;                                         \
    int ch = c & 511;                                                         \
    float bias = bqk[c];                                                      \
    float rspv = 1.0f / log1pf(expf(scale_p[ch]));                            \
    int tt = ch >> 1;                                                         \
    const float* lbase = lut + (tt & 127);                                    \
    int use_i = (tt < 128);                                                   \
    float* dst = (c < C_DIM) ? qW : kW;                                       \
    EPI_I(0, A0); EPI_I(1, A1); EPI_I(2, A2); EPI_I(3, A3);                   \
} while (0)

__global__ __launch_bounds__(256, 1) void gemm_mfma_kernel(
    const unsigned short* __restrict__ xb,   // (32768,512) bf16
    const unsigned short* __restrict__ Wb,   // (1024,512) bf16
    const float* __restrict__ bqk,           // (1024)
    const float* __restrict__ scale_p,       // (512)
    const float* __restrict__ lut,           // (2,64,128) cos/sin
    float* __restrict__ qW,                  // (32768,512)
    float* __restrict__ kW)                  // (32768,512)
{
    __shared__ char lds[16384];
    char* As = lds;            // 128 rows x 32 bf16 (64B/row), chunk-swizzled
    char* Bs = lds + 8192;

    const int t = threadIdx.x;
    const int wave = t >> 6;
    const int lane = t & 63;
    const int quad = lane >> 4;
    const int l16 = lane & 15;
    const int is_im = l16 & 1;

    // XCD-aware swizzle: flat = bx + 8*by; xcd = flat&7 (round-robin);
    // each xcd gets all 8 n-tiles of 32 consecutive m-tiles.
    const int flat = blockIdx.x + 8 * blockIdx.y;
    const int xcd = flat & 7;
    const int ii_ = flat >> 3;
    const int n0 = (ii_ & 7) * GBN;
    const int m0 = (xcd * 32 + (ii_ >> 3)) * GBM;

    const int wm = (wave >> 1) * 64;
    const int wn = (wave & 1) * 64;

    const int srow = t >> 2;    // staging row within 64-row half
    const int sj = t & 3;       // LDS 16B-chunk slot

    f32x4 acc00 = {0.f,0.f,0.f,0.f}, acc01 = {0.f,0.f,0.f,0.f},
          acc02 = {0.f,0.f,0.f,0.f}, acc03 = {0.f,0.f,0.f,0.f},
          acc10 = {0.f,0.f,0.f,0.f}, acc11 = {0.f,0.f,0.f,0.f},
          acc12 = {0.f,0.f,0.f,0.f}, acc13 = {0.f,0.f,0.f,0.f},
          acc20 = {0.f,0.f,0.f,0.f}, acc21 = {0.f,0.f,0.f,0.f},
          acc22 = {0.f,0.f,0.f,0.f}, acc23 = {0.f,0.f,0.f,0.f},
          acc30 = {0.f,0.f,0.f,0.f}, acc31 = {0.f,0.f,0.f,0.f},
          acc32 = {0.f,0.f,0.f,0.f}, acc33 = {0.f,0.f,0.f,0.f};

    for (int k0 = 0; k0 < C_DIM; k0 += GBK) {
        __syncthreads();   // previous iter's LDS reads done
#pragma unroll
        for (int p = 0; p < 2; ++p) {
            int m = p * 64 + srow;
            int jp = sj ^ ((m >> 1) & 3);   // global chunk stored at slot sj
            const unsigned short* ga = xb + (size_t)(m0 + m) * C_DIM + k0 + jp * 8;
            async_ld16(As + p * 4096 + wave * 1024, ga);
            const unsigned short* gb = Wb + (size_t)(n0 + m) * C_DIM + k0 + jp * 8;
            async_ld16(Bs + p * 4096 + wave * 1024, gb);
        }
        __syncthreads();   // staging visible

        const int swz = (l16 >> 1) & 3;
        const int co = (quad ^ swz) * 16;
        bf16x8 a0 = *(const bf16x8*)(As + (wm + 0 * 16 + l16) * 64 + co);
        bf16x8 a1 = *(const bf16x8*)(As + (wm + 1 * 16 + l16) * 64 + co);
        bf16x8 a2 = *(const bf16x8*)(As + (wm + 2 * 16 + l16) * 64 + co);
        bf16x8 a3 = *(const bf16x8*)(As + (wm + 3 * 16 + l16) * 64 + co);
        bf16x8 b0 = *(const bf16x8*)(Bs + (wn + 0 * 16 + l16) * 64 + co);
        bf16x8 b1 = *(const bf16x8*)(Bs + (wn + 1 * 16 + l16) * 64 + co);
        bf16x8 b2 = *(const bf16x8*)(Bs + (wn + 2 * 16 + l16) * 64 + co);
        bf16x8 b3 = *(const bf16x8*)(Bs + (wn + 3 * 16 + l16) * 64 + co);

        acc00 = __builtin_amdgcn_mfma_f32_16x16x32_bf16(a0, b0, acc00, 0, 0, 0);
        acc01 = __builtin_amdgcn_mfma_f32_16x16x32_bf16(a0, b1, acc01, 0, 0, 0);
        acc02 = __builtin_amdgcn_mfma_f32_16x16x32_bf16(a0, b2, acc02, 0, 0, 0);
        acc03 = __builtin_amdgcn_mfma_f32_16x16x32_bf16(a0, b3, acc03, 0, 0, 0);
        acc10 = __builtin_amdgcn_mfma_f32_16x16x32_bf16(a1, b0, acc10, 0, 0, 0);
        acc11 = __builtin_amdgcn_mfma_f32_16x16x32_bf16(a1, b1, acc11, 0, 0, 0);
        acc12 = __builtin_amdgcn_mfma_f32_16x16x32_bf16(a1, b2, acc12, 0, 0, 0);
        acc13 = __builtin_amdgcn_mfma_f32_16x16x32_bf16(a1, b3, acc13, 0, 0, 0);
        acc20 = __builtin_amdgcn_mfma_f32_16x16x32_bf16(a2, b0, acc20, 0, 0, 0);
        acc21 = __builtin_amdgcn_mfma_f32_16x16x32_bf16(a2, b1, acc21, 0, 0, 0);
        acc22 = __builtin_amdgcn_mfma_f32_16x16x32_bf16(a2, b2, acc22, 0, 0, 0);
        acc23 = __builtin_amdgcn_mfma_f32_16x16x32_bf16(a2, b3, acc23, 0, 0, 0);
        acc30 = __builtin_amdgcn_mfma_f32_16x16x32_bf16(a3, b0, acc30, 0, 0, 0);
        acc31 = __builtin_amdgcn_mfma_f32_16x16x32_bf16(a3, b1, acc31, 0, 0, 0);
        acc32 = __builtin_amdgcn_mfma_f32_16x16x32_bf16(a3, b2, acc32, 0, 0, 0);
        acc33 = __builtin_amdgcn_mfma_f32_16x16x32_bf16(a3, b3, acc33, 0, 0, 0);
    }

    // Epilogue: bias + RoPE (LUT) + elu+1 + /softplus. D[m=quad*4+r][n=l16].
    EPI_J(0, acc00, acc10, acc20, acc30);
    EPI_J(1, acc01, acc11, acc21, acc31);
    EPI_J(2, acc02, acc12, acc22, acc32);
    EPI_J(3, acc03, acc13, acc23, acc33);
}

// ---------------------------------------------------------------------------
// Pass 2: per-row norms -> s = ||v|| / ||v^3||  (for q and k)
// ---------------------------------------------------------------------------
__global__ __launch_bounds__(256) void norm_kernel(
    const float* __restrict__ qW, const float* __restrict__ kW,
    float* __restrict__ sq, float* __restrict__ sk)
{
    int wave = threadIdx.x >> 6;
    int lane = threadIdx.x & 63;
    int m = blockIdx.x * 4 + wave;
    const float* qr = qW + (size_t)m * C_DIM;
    const float* kr = kW + (size_t)m * C_DIM;
    float q2 = 0.f, q6 = 0.f, k2 = 0.f, k6 = 0.f;
#pragma unroll
    for (int l = 0; l < 8; ++l) {
        float q = qr[lane + l * 64];
        float k = kr[lane + l * 64];
        float qq = q * q, kk = k * k;
        q2 += qq;
        k2 += kk;
        q6 += qq * qq * qq;
        k6 += kk * kk * kk;
    }
#pragma unroll
    for (int off = 32; off > 0; off >>= 1) {
        q2 += __shfl_down(q2, off);
        q6 += __shfl_down(q6, off);
        k2 += __shfl_down(k2, off);
        k6 += __shfl_down(k6, off);
    }
    if (lane == 0) {
        sq[m] = sqrtf(q2) / sqrtf(q6);
        sk[m] = sqrtf(k2) / sqrtf(k6);
    }
}

// ---------------------------------------------------------------------------
// Pass 3a: partial kv[d][e] = sum_n k_f[n,d]*v[n,e] and km[d] = sum_n k_f[n,d]
// ---------------------------------------------------------------------------
__global__ __launch_bounds__(256) void kv_partial_kernel(
    const float* __restrict__ x, const float* __restrict__ kW,
    const float* __restrict__ sk,
    float* __restrict__ kvp, float* __restrict__ kmp)
{
    int g = blockIdx.x >> 2;       // (b*16+h)
    int split = blockIdx.x & 3;
    int b = g >> 4, h = g & 15;
    int n_start = split * 1024;

    __shared__ float kf[64][36];
    __shared__ float vv[64][36];

    int t = threadIdx.x;
    int col = t & 31, rowb = t >> 5;
    int e = t & 31, d0 = (t >> 5) * 4;
    float acc[4] = {0.f, 0.f, 0.f, 0.f};
    float kmacc = 0.f;

    for (int n0 = n_start; n0 < n_start + 1024; n0 += 64) {
        __syncthreads();
#pragma unroll
        for (int r = 0; r < 8; ++r) {
            int row = r * 8 + rowb;
            int n = n0 + row;
            size_t base = ((size_t)(b * N_TOK + n)) * C_DIM + h * HDIM + col;
            float kvl = kW[base];
            float skv = sk[b * N_TOK + n];
            kf[row][col] = kvl * kvl * kvl * skv;
            vv[row][col] = x[base];
        }
        __syncthreads();
        for (int nn = 0; nn < 64; ++nn) {
            float vval = vv[nn][e];
            float4 k4 = *(const float4*)&kf[nn][d0];
            acc[0] += k4.x * vval;
            acc[1] += k4.y * vval;
            acc[2] += k4.z * vval;
            acc[3] += k4.w * vval;
        }
        if (t < 32) {
            for (int nn = 0; nn < 64; ++nn) kmacc += kf[nn][t];
        }
    }
    size_t pbase = (size_t)blockIdx.x * 1024;
#pragma unroll
    for (int di = 0; di < 4; ++di)
        kvp[pbase + (size_t)(d0 + di) * 32 + e] = acc[di];
    if (t < 32) kmp[blockIdx.x * 32 + t] = kmacc;
}

// Pass 3b: reduce the 4 splits; scale by 1/N
__global__ __launch_bounds__(256) void kv_reduce_kernel(
    const float* __restrict__ kvp, const float* __restrict__ kmp,
    float* __restrict__ kv, float* __restrict__ km)
{
    int g = blockIdx.x;   // 128
    int t = threadIdx.x;
    for (int idx = t; idx < 1024; idx += 256) {
        float s = 0.f;
#pragma unroll
        for (int sp = 0; sp < 4; ++sp)
            s += kvp[((size_t)(g * 4 + sp)) * 1024 + idx];
        kv[(size_t)g * 1024 + idx] = s * (1.0f / 4096.0f);
    }
    if (t < 32) {
        float s = 0.f;
#pragma unroll
        for (int sp = 0; sp < 4; ++sp) s += kmp[(g * 4 + sp) * 32 + t];
        km[g * 32 + t] = s * (1.0f / 4096.0f);
    }
}

// ---------------------------------------------------------------------------
// Pass 4: out[b,n,h*32+e] = z * sum_d q_f[n,d] kv[d,e],  z = 1/(q_f . km + 1e-6)
// ---------------------------------------------------------------------------
__global__ __launch_bounds__(256) void attn_out_kernel(
    const float* __restrict__ qW, const float* __restrict__ sq,
    const float* __restrict__ kv, const float* __restrict__ km,
    float* __restrict__ out)
{
    int g = blockIdx.x;
    int b = g >> 4, h = g & 15;
    int n0 = blockIdx.y * 128;

    __shared__ float kvs[32][33];
    __shared__ float kms[32];
    __shared__ float qf[8][33];

    int t = threadIdx.x;
    for (int idx = t; idx < 1024; idx += 256)
        kvs[idx >> 5][idx & 31] = kv[(size_t)g * 1024 + idx];
    if (t < 32) kms[t] = km[g * 32 + t];
    __syncthreads();

    int e = t & 31, nl = t >> 5;
    for (int chunk = 0; chunk < 128; chunk += 8) {
        int n = n0 + chunk + nl;
        size_t base = ((size_t)(b * N_TOK + n)) * C_DIM + h * HDIM;
        float q = qW[base + e];
        qf[nl][e] = q * q * q * sq[b * N_TOK + n];
        __syncthreads();
        float s1 = 0.f, s2 = 0.f;
#pragma unroll
        for (int d = 0; d < 32; ++d) {
            float qd = qf[nl][d];
            s1 += qd * kvs[d][e];
            s2 += qd * kms[d];
        }
        float z = 1.0f / (s2 + 1e-6f);
        out[base + e] = s1 * z;
        __syncthreads();
    }
}

// ---------------------------------------------------------------------------
// Pass 5: out += depthwise conv5x5(x) + bias
// Register-blocked: each thread = 4 j-positions x 4 channels (float4).
// ---------------------------------------------------------------------------
__global__ __launch_bounds__(256, 2) void conv_kernel(
    const float* __restrict__ x, const float* __restrict__ w,
    const float* __restrict__ bias, float* __restrict__ out)
{
    __shared__ float wl[25][32];
    int t = threadIdx.x;
    for (int idx = t; idx < 800; idx += 256) {
        int o = idx & 31, tap = idx >> 5;
        wl[tap][o] = w[o * 25 + tap];
    }
    __syncthreads();

    int bi = blockIdx.x >> 3;        // b*64 + i
    int part = blockIdx.x & 7;
    int b = bi >> 6, i = bi & 63;
    int jg = part * 2 + (t >> 7);    // j-group of 4
    int cg = t & 127;                // channel group of 4
    int j0 = jg * 4;
    int o4 = (cg & 7) * 4;           // kernel-channel base (c%32)

    const float* xbase = x + ((size_t)b * N_TOK) * C_DIM + cg * 4;

    float4 b4 = *(const float4*)&bias[o4];
    float4 acc[4] = {b4, b4, b4, b4};

#pragma unroll
    for (int ki = 0; ki < 5; ++ki) {
        int ii = i + ki - 2;
        if (ii < 0 || ii >= IMG_H) continue;      // wave-uniform
        const float* xr = xbase + (size_t)ii * 64 * C_DIM;
        float4 row[8];
#pragma unroll
        for (int jx = 0; jx < 8; ++jx) {
            int jj = j0 + jx - 2;
            row[jx] = (jj >= 0 && jj < IMG_W)
                          ? *(const float4*)(xr + (size_t)jj * C_DIM)
                          : make_float4(0.f, 0.f, 0.f, 0.f);
        }
#pragma unroll
        for (int kj = 0; kj < 5; ++kj) {
            float4 w4 = *(const float4*)&wl[ki * 5 + kj][o4];
#pragma unroll
            for (int jo = 0; jo < 4; ++jo) {
                acc[jo].x += w4.x * row[jo + kj].x;
                acc[jo].y += w4.y * row[jo + kj].y;
                acc[jo].z += w4.z * row[jo + kj].z;
                acc[jo].w += w4.w * row[jo + kj].w;
            }
        }
    }

    float* op = out + ((size_t)(b * N_TOK + i * 64 + j0)) * C_DIM + cg * 4;
#pragma unroll
    for (int jo = 0; jo < 4; ++jo) {
        float4 cur = *(float4*)(op + (size_t)jo * C_DIM);
        cur.x += acc[jo].x;
        cur.y += acc[jo].y;
        cur.z += acc[jo].z;
        cur.w += acc[jo].w;
        *(float4*)(op + (size_t)jo * C_DIM) = cur;
    }
}

// ---------------------------------------------------------------------------
extern "C" void kernel_launch(void* const* d_in, const int* in_sizes, int n_in,
                              void* d_out, int out_size, void* d_ws, size_t ws_size,
                              hipStream_t stream) {
    const float* x       = (const float*)d_in[0];
    const float* Wqk     = (const float*)d_in[1];
    const float* bqk     = (const float*)d_in[2];
    const float* scale_p = (const float*)d_in[3];
    const float* dwc_w   = (const float*)d_in[4];
    const float* dwc_b   = (const float*)d_in[5];
    float* out = (float*)d_out;
    float* ws = (float*)d_ws;

    // workspace layout (floats): qW | sq | sk | kvp | kmp | kv | km | xb | Wb | lut
    float* qW  = ws;                                  // 16,777,216
    float* sq  = qW + (size_t)M_ROWS * C_DIM;         // 32,768
    float* sk  = sq + M_ROWS;                         // 32,768
    float* kvp = sk + M_ROWS;                         // 524,288
    float* kmp = kvp + 512 * 1024;                    // 16,384
    float* kv  = kmp + 512 * 32;                      // 131,072
    float* km  = kv + 128 * 1024;                     // 2,048
    unsigned short* xb = (unsigned short*)(km + 2048);        // bf16 x
    unsigned short* Wb = xb + (size_t)M_ROWS * C_DIM;         // bf16 W
    float* lut = (float*)(Wb + (size_t)QK_COLS * C_DIM);      // 16384 floats
    float* kW  = out;   // k staged in d_out; consumed before pass 4 overwrites

    cvt_bf16_kernel<<<(M_ROWS * C_DIM) / 1024, 256, 0, stream>>>(x, xb);
    cvt_bf16_kernel<<<(QK_COLS * C_DIM) / 1024, 256, 0, stream>>>(Wqk, Wb);
    rope_lut_kernel<<<32, 256, 0, stream>>>(lut);

    dim3 gg(QK_COLS / GBN, M_ROWS / GBM);
    gemm_mfma_kernel<<<gg, 256, 0, stream>>>(xb, Wb, bqk, scale_p, lut, qW, kW);

    norm_kernel<<<M_ROWS / 4, 256, 0, stream>>>(qW, kW, sq, sk);

    kv_partial_kernel<<<512, 256, 0, stream>>>(x, kW, sk, kvp, kmp);
    kv_reduce_kernel<<<128, 256, 0, stream>>>(kvp, kmp, kv, km);

    dim3 g4(128, 32);
    attn_out_kernel<<<g4, 256, 0, stream>>>(qW, sq, kv, km, out);

    conv_kernel<<<M_ROWS / 8, 256, 0, stream>>>(x, dwc_w, dwc_b, out);
}